// Round 1
// baseline (1242.456 us; speedup 1.0000x reference)
//
#include <hip/hip_runtime.h>
#include <math.h>

#define BB 16384
#define DD 1024
#define RR 64
#define EE 4
#define ER 256   // EE*RR

// K1: t1[b, e*64+r] = tanh(sum_d x[b,d] * V[(e*DD+d)*RR + r])
// 128x64 tile (grid.y = expert), 256 threads, micro 8x4, Kt=32
__global__ __launch_bounds__(256) void gemm1_tanh(const float* __restrict__ x,
                                                  const float* __restrict__ Vl,
                                                  float* __restrict__ t1) {
    const int row0 = blockIdx.x * 128;
    const int e = blockIdx.y;
    __shared__ float xs[128 * 36];   // pad 36: 16B-aligned rows, ty-groups 4 banks apart
    __shared__ float vs[32 * 64];
    const int tid = threadIdx.x;
    const int tx = tid & 15, ty = tid >> 4;
    float acc[8][4] = {};
    const float* Ve = Vl + (size_t)e * (DD * RR);
    for (int k0 = 0; k0 < DD; k0 += 32) {
        #pragma unroll
        for (int p = 0; p < 4; ++p) {            // xs: 128x32 = 1024 float4
            int f = tid + p * 256;
            int r = f >> 3;
            int c = (f & 7) * 4;
            float4 v = *(const float4*)&x[(size_t)(row0 + r) * DD + k0 + c];
            *(float4*)&xs[r * 36 + c] = v;
        }
        #pragma unroll
        for (int p = 0; p < 2; ++p) {            // vs: 32x64 = 512 float4
            int f = tid + p * 256;
            int r = f >> 4;
            int c = (f & 15) * 4;
            float4 v = *(const float4*)&Ve[(size_t)(k0 + r) * RR + c];
            *(float4*)&vs[r * 64 + c] = v;
        }
        __syncthreads();
        #pragma unroll
        for (int kk = 0; kk < 32; ++kk) {
            float4 bv = *(const float4*)&vs[kk * 64 + tx * 4];
            float bq[4] = {bv.x, bv.y, bv.z, bv.w};
            #pragma unroll
            for (int ii = 0; ii < 8; ++ii) {
                float a = xs[(ty + ii * 16) * 36 + kk];
                acc[ii][0] += a * bq[0];
                acc[ii][1] += a * bq[1];
                acc[ii][2] += a * bq[2];
                acc[ii][3] += a * bq[3];
            }
        }
        __syncthreads();
    }
    #pragma unroll
    for (int ii = 0; ii < 8; ++ii) {
        int gb = row0 + ty + ii * 16;
        float4 o;
        o.x = tanhf(acc[ii][0]);
        o.y = tanhf(acc[ii][1]);
        o.z = tanhf(acc[ii][2]);
        o.w = tanhf(acc[ii][3]);
        *(float4*)&t1[(size_t)gb * ER + e * 64 + tx * 4] = o;
    }
}

// K2: per row b: logits -> softmax gates; w[b,e*64+r] = gate[e]*tanh(sum_s C[e,r,s]*t1[b,e*64+s])
// In-place over t1 (row staged in LDS first). One block (256 thr, 4 waves = 4 experts) per row.
__global__ __launch_bounds__(256) void mix_kernel(const float* __restrict__ x,
                                                  const float* __restrict__ gate_w,
                                                  const float* __restrict__ Cl,
                                                  float* t1w) {
    const int b = blockIdx.x;
    __shared__ float xrow[DD];
    __shared__ float trow[ER];
    __shared__ float lg[EE];
    const int tid = threadIdx.x;
    {
        int f = tid * 4;
        *(float4*)&xrow[f] = *(const float4*)&x[(size_t)b * DD + f];
    }
    trow[tid] = t1w[(size_t)b * ER + tid];
    __syncthreads();
    const int e = tid >> 6;      // wave id == expert
    const int lane = tid & 63;
    float ps = 0.f;
    for (int d = lane; d < DD; d += 64) ps += xrow[d] * gate_w[e * DD + d];
    #pragma unroll
    for (int off = 32; off > 0; off >>= 1) ps += __shfl_down(ps, off, 64);
    if (lane == 0) lg[e] = ps;
    __syncthreads();
    float l0 = lg[0], l1 = lg[1], l2 = lg[2], l3 = lg[3];
    float m = fmaxf(fmaxf(l0, l1), fmaxf(l2, l3));
    float e0 = __expf(l0 - m), e1 = __expf(l1 - m), e2 = __expf(l2 - m), e3 = __expf(l3 - m);
    float inv = 1.f / (e0 + e1 + e2 + e3);
    float gate = (e == 0 ? e0 : e == 1 ? e1 : e == 2 ? e2 : e3) * inv;
    const float* Crow = Cl + (size_t)(e * RR + lane) * RR;
    float acc = 0.f;
    #pragma unroll
    for (int s = 0; s < RR; s += 4) {
        float4 c4 = *(const float4*)&Crow[s];
        acc += c4.x * trow[e * 64 + s + 0] + c4.y * trow[e * 64 + s + 1]
             + c4.z * trow[e * 64 + s + 2] + c4.w * trow[e * 64 + s + 3];
    }
    t1w[(size_t)b * ER + tid] = gate * tanhf(acc);
}

// K3: out[b,d] = x0[b,d]*(sum_{e,r} w[b,e*64+r]*U[(e*DD+d)*RR+r] + bias[d]) + xl[b,d]
// 128x64 tile, 256 threads, micro 8x4, K=256 in 4 expert chunks. In-place safe (out may == xl).
__global__ __launch_bounds__(256) void gemm2_combine(const float* __restrict__ w,
                                                     const float* __restrict__ Ul,
                                                     const float* __restrict__ x0,
                                                     const float* xl,
                                                     const float* __restrict__ biasl,
                                                     float* out) {
    const int row0 = blockIdx.x * 128;
    const int d0 = blockIdx.y * 64;
    __shared__ float ws_[128 * 68];  // pad 68: aligned float4 writes, ty-groups 8 banks apart
    __shared__ float us[64 * 65];    // us[d][r]; pad 65 -> NT b-reads 2-way (free)
    const int tid = threadIdx.x;
    const int tx = tid & 15, ty = tid >> 4;
    float acc[8][4] = {};
    for (int e = 0; e < EE; ++e) {
        #pragma unroll
        for (int p = 0; p < 8; ++p) {            // w tile: 128x64 = 2048 float4
            int f = tid + p * 256;
            int r = f >> 4;
            int c = (f & 15) * 4;
            float4 v = *(const float4*)&w[(size_t)(row0 + r) * ER + e * 64 + c];
            *(float4*)&ws_[r * 68 + c] = v;
        }
        #pragma unroll
        for (int p = 0; p < 4; ++p) {            // U tile: us[d][r], 64x64
            int f = tid + p * 256;
            int dd = f >> 4;
            int c = (f & 15) * 4;
            float4 v = *(const float4*)&Ul[((size_t)e * DD + d0 + dd) * RR + c];
            us[dd * 65 + c + 0] = v.x;
            us[dd * 65 + c + 1] = v.y;
            us[dd * 65 + c + 2] = v.z;
            us[dd * 65 + c + 3] = v.w;
        }
        __syncthreads();
        #pragma unroll 8
        for (int kk = 0; kk < 64; ++kk) {
            float bq[4];
            bq[0] = us[(tx * 4 + 0) * 65 + kk];
            bq[1] = us[(tx * 4 + 1) * 65 + kk];
            bq[2] = us[(tx * 4 + 2) * 65 + kk];
            bq[3] = us[(tx * 4 + 3) * 65 + kk];
            #pragma unroll
            for (int ii = 0; ii < 8; ++ii) {
                float a = ws_[(ty + ii * 16) * 68 + kk];
                acc[ii][0] += a * bq[0];
                acc[ii][1] += a * bq[1];
                acc[ii][2] += a * bq[2];
                acc[ii][3] += a * bq[3];
            }
        }
        __syncthreads();
    }
    #pragma unroll
    for (int ii = 0; ii < 8; ++ii) {
        int gb = row0 + ty + ii * 16;
        size_t base = (size_t)gb * DD + d0 + tx * 4;
        float4 xv  = *(const float4*)&x0[base];
        float4 xlv = *(const float4*)&xl[base];
        float4 bv  = *(const float4*)&biasl[d0 + tx * 4];
        float4 o;
        o.x = xv.x * (acc[ii][0] + bv.x) + xlv.x;
        o.y = xv.y * (acc[ii][1] + bv.y) + xlv.y;
        o.z = xv.z * (acc[ii][2] + bv.z) + xlv.z;
        o.w = xv.w * (acc[ii][3] + bv.w) + xlv.w;
        *(float4*)&out[base] = o;
    }
}

extern "C" void kernel_launch(void* const* d_in, const int* in_sizes, int n_in,
                              void* d_out, int out_size, void* d_ws, size_t ws_size,
                              hipStream_t stream) {
    const float* inputs = (const float*)d_in[0];
    const float* U      = (const float*)d_in[1];
    const float* V      = (const float*)d_in[2];
    const float* C      = (const float*)d_in[3];
    const float* gw     = (const float*)d_in[4];
    const float* bias   = (const float*)d_in[5];
    float* out = (float*)d_out;
    float* t1  = (float*)d_ws;   // B*ER floats (16 MB), reused in-place as gated w

    for (int i = 0; i < 3; ++i) {
        const float* x = (i == 0) ? inputs : out;   // d_out doubles as x_l buffer
        gemm1_tanh<<<dim3(BB / 128, EE), 256, 0, stream>>>(
            x, V + (size_t)i * EE * DD * RR, t1);
        mix_kernel<<<dim3(BB), 256, 0, stream>>>(
            x, gw, C + (size_t)i * EE * RR * RR, t1);
        gemm2_combine<<<dim3(BB / 128, DD / 64), 256, 0, stream>>>(
            t1, U + (size_t)i * EE * DD * RR, inputs, x,
            bias + (size_t)i * DD, out);
    }
}